// Round 4
// baseline (5934.311 us; speedup 1.0000x reference)
//
#include <hip/hip_runtime.h>
#include <hip/hip_bf16.h>
#include <math.h>

#define DIM 2048
#define NH 16
#define HD 128
#define WIN 512

typedef __hip_bfloat16 bf16;

// ---------- conversion helpers ----------
__device__ inline float toF(const bf16 v) { return __bfloat162float(v); }
__device__ inline float toF(const float v) { return v; }
template <typename T> __device__ inline T fromF(float v);
template <> __device__ inline float fromF<float>(float v) { return v; }
template <> __device__ inline bf16 fromF<bf16>(float v) { return __float2bfloat16(v); }

// ---------- GEMM: C[m,n] = sum_k A[m,k] * B[n,k]  (B transposed layout) ----------
// Tiles: BM=BN=64, BK=32. 256 threads, each computes 4x4 micro-tile.
template <typename TA, typename TB, typename TC>
__global__ __launch_bounds__(256) void gemm_bt(const TA* __restrict__ A,
                                               const TB* __restrict__ B,
                                               TC* __restrict__ C,
                                               int M, int N, int K) {
    __shared__ float As[64][33];
    __shared__ float Bs[64][33];
    const int n0 = blockIdx.x * 64;
    const int m0 = blockIdx.y * 64;
    const int tid = threadIdx.x;
    const int tx = tid % 16;  // n-direction
    const int ty = tid / 16;  // m-direction
    float acc[4][4] = {};

    for (int k0 = 0; k0 < K; k0 += 32) {
        // Cooperative load of A (64x32) and B (64x32) tiles: 8 elems/thread each.
        const int r = tid / 4;
        const int c = (tid % 4) * 8;
        const TA* srca = A + (size_t)(m0 + r) * K + k0 + c;
        const TB* srcb = B + (size_t)(n0 + r) * K + k0 + c;
#pragma unroll
        for (int u = 0; u < 8; ++u) As[r][c + u] = toF(srca[u]);
#pragma unroll
        for (int u = 0; u < 8; ++u) Bs[r][c + u] = toF(srcb[u]);
        __syncthreads();

#pragma unroll
        for (int kk = 0; kk < 32; ++kk) {
            float a[4], b[4];
#pragma unroll
            for (int i = 0; i < 4; ++i) a[i] = As[ty * 4 + i][kk];
#pragma unroll
            for (int j = 0; j < 4; ++j) b[j] = Bs[tx * 4 + j][kk];
#pragma unroll
            for (int i = 0; i < 4; ++i)
#pragma unroll
                for (int j = 0; j < 4; ++j) acc[i][j] += a[i] * b[j];
        }
        __syncthreads();
    }

#pragma unroll
    for (int i = 0; i < 4; ++i)
#pragma unroll
        for (int j = 0; j < 4; ++j)
            C[(size_t)(m0 + ty * 4 + i) * N + n0 + tx * 4 + j] = fromF<TC>(acc[i][j]);
}

// ---------- RoPE (in-place on Q and K, bf16 storage, fp32 math) ----------
__global__ void rope_qk(bf16* __restrict__ Q, bf16* __restrict__ K, int S) {
    const int p = blockIdx.x * blockDim.x + threadIdx.x;
    const int total = S * NH * (HD / 2);
    if (p >= total) return;
    const int i = p % (HD / 2);        // frequency index
    const int rem = p / (HD / 2);
    const int h = rem % NH;
    const int s = rem / NH;
    const float inv = powf(10000.0f, -(float)(2 * i) / (float)HD);
    const float ang = (float)s * inv;
    float sn, cs;
    sincosf(ang, &sn, &cs);
    const size_t base = (size_t)s * DIM + h * HD + 2 * i;
    const float q1 = toF(Q[base]), q2 = toF(Q[base + 1]);
    Q[base] = fromF<bf16>(q1 * cs - q2 * sn);
    Q[base + 1] = fromF<bf16>(q1 * sn + q2 * cs);
    const float k1 = toF(K[base]), k2 = toF(K[base + 1]);
    K[base] = fromF<bf16>(k1 * cs - k2 * sn);
    K[base + 1] = fromF<bf16>(k1 * sn + k2 * cs);
}

// ---------- sliding-window attention: one block per (query i, head h) ----------
__global__ __launch_bounds__(256) void swa_attn(const bf16* __restrict__ Q,
                                                const bf16* __restrict__ K,
                                                const bf16* __restrict__ V,
                                                bf16* __restrict__ O, int S) {
    const int i = blockIdx.x;
    const int h = blockIdx.y;
    const int tid = threadIdx.x;
    const int lane = tid & 63;
    const int wave = tid >> 6;

    const int jlo = (i >= WIN - 1) ? i - (WIN - 1) : 0;
    const int cnt = i - jlo + 1;  // <= 512

    __shared__ float sc[WIN];
    __shared__ float red[256];

    // Per-lane Q fragment: dims 2*lane, 2*lane+1
    const bf16* qrow = Q + (size_t)i * DIM + h * HD;
    const float qa = toF(qrow[2 * lane]);
    const float qb = toF(qrow[2 * lane + 1]);
    const float scale = 0.08838834764831845f;  // 1/sqrt(128)

    // Phase 1: scores. Each wave handles keys jj = wave, wave+4, ...
    for (int jj = wave; jj < cnt; jj += 4) {
        const bf16* krow = K + (size_t)(jlo + jj) * DIM + h * HD;
        float pa = qa * toF(krow[2 * lane]) + qb * toF(krow[2 * lane + 1]);
#pragma unroll
        for (int off = 32; off > 0; off >>= 1) pa += __shfl_down(pa, off, 64);
        if (lane == 0) sc[jj] = pa * scale;
    }
    __syncthreads();

    // Phase 2: softmax over sc[0..cnt)
    float m = -1e30f;
    for (int jj = tid; jj < cnt; jj += 256) m = fmaxf(m, sc[jj]);
    red[tid] = m;
    __syncthreads();
    for (int s2 = 128; s2 > 0; s2 >>= 1) {
        if (tid < s2) red[tid] = fmaxf(red[tid], red[tid + s2]);
        __syncthreads();
    }
    m = red[0];
    __syncthreads();

    float lsum = 0.f;
    for (int jj = tid; jj < cnt; jj += 256) {
        const float e = __expf(sc[jj] - m);
        sc[jj] = e;
        lsum += e;
    }
    red[tid] = lsum;
    __syncthreads();
    for (int s2 = 128; s2 > 0; s2 >>= 1) {
        if (tid < s2) red[tid] += red[tid + s2];
        __syncthreads();
    }
    const float rinv = 1.0f / red[0];
    __syncthreads();

    // Phase 3: O[d] = rinv * sum_j sc[jj] * V[j][d]; two key-partitions per dim.
    const int d = tid & 127;
    const int part = tid >> 7;
    float acc = 0.f;
    for (int jj = part; jj < cnt; jj += 2) {
        acc += sc[jj] * toF(V[(size_t)(jlo + jj) * DIM + h * HD + d]);
    }
    red[tid] = acc;
    __syncthreads();
    if (tid < 128) {
        O[(size_t)i * DIM + h * HD + tid] = fromF<bf16>((red[tid] + red[tid + 128]) * rinv);
    }
}

extern "C" void kernel_launch(void* const* d_in, const int* in_sizes, int n_in,
                              void* d_out, int out_size, void* d_ws, size_t ws_size,
                              hipStream_t stream) {
    const float* x  = (const float*)d_in[0];
    const float* Wq = (const float*)d_in[1];
    const float* Wk = (const float*)d_in[2];
    const float* Wv = (const float*)d_in[3];
    const float* Wo = (const float*)d_in[4];
    float* out = (float*)d_out;   // reference output dtype is float32

    const int S = in_sizes[0] / DIM;  // 4096
    const size_t elems = (size_t)S * DIM;

    bf16* Q = (bf16*)d_ws;
    bf16* K = Q + elems;
    bf16* V = K + elems;
    bf16* A = V + elems;

    dim3 gblk(DIM / 64, S / 64);
    gemm_bt<float, float, bf16><<<gblk, 256, 0, stream>>>(x, Wq, Q, S, DIM, DIM);
    gemm_bt<float, float, bf16><<<gblk, 256, 0, stream>>>(x, Wk, K, S, DIM, DIM);
    gemm_bt<float, float, bf16><<<gblk, 256, 0, stream>>>(x, Wv, V, S, DIM, DIM);

    const int pairs = S * NH * (HD / 2);
    rope_qk<<<(pairs + 255) / 256, 256, 0, stream>>>(Q, K, S);

    swa_attn<<<dim3(S, NH), 256, 0, stream>>>(Q, K, V, A, S);

    gemm_bt<bf16, float, float><<<gblk, 256, 0, stream>>>(A, Wo, out, S, DIM, DIM);
}

// Round 5
// 3587.489 us; speedup vs baseline: 1.6542x; 1.6542x over previous
//
#include <hip/hip_runtime.h>
#include <hip/hip_bf16.h>
#include <math.h>

#define DIM 2048
#define NH 16
#define HD 128
#define WIN 512

typedef __hip_bfloat16 bf16;
using frag8 = __attribute__((ext_vector_type(8))) short;  // 8 bf16 (4 VGPRs)
using facc4 = __attribute__((ext_vector_type(4))) float;  // 4 fp32 acc

// ---------- conversion helpers ----------
__device__ inline float toF(const bf16 v) { return __bfloat162float(v); }
__device__ inline float toF(const float v) { return v; }
template <typename T> __device__ inline T fromF(float v);
template <> __device__ inline float fromF<float>(float v) { return v; }
template <> __device__ inline bf16 fromF<bf16>(float v) { return __float2bfloat16(v); }

// fp32 -> bf16 bits, round-to-nearest-even (exact for finite values)
__device__ inline unsigned bfb(float x) {
    unsigned u = __float_as_uint(x);
    u += 0x7fffu + ((u >> 16) & 1u);
    return u >> 16;
}

// Stage 8 contiguous elements as 8 packed bf16 (one uint4)
template <typename T> struct Stage;
template <> struct Stage<float> {
    __device__ static uint4 load8(const float* p) {
        const float4 v0 = *(const float4*)p;
        const float4 v1 = *(const float4*)(p + 4);
        uint4 r;
        r.x = bfb(v0.x) | (bfb(v0.y) << 16);
        r.y = bfb(v0.z) | (bfb(v0.w) << 16);
        r.z = bfb(v1.x) | (bfb(v1.y) << 16);
        r.w = bfb(v1.z) | (bfb(v1.w) << 16);
        return r;
    }
};
template <> struct Stage<bf16> {
    __device__ static uint4 load8(const bf16* p) { return *(const uint4*)p; }
};

// ---------- MFMA GEMM: C[m,n] = sum_k A[m,k] * B[n,k]  (B row-major = B^T layout) ----------
// 128x128 tile, BK=32, 256 threads = 4 waves in 2x2, each wave 4x4 tiles of 16x16x32 bf16 MFMA.
// A is fp32 or bf16 (converted to bf16 during staging); B is fp32 weights.
template <typename TA, typename TC>
__global__ __launch_bounds__(256) void gemm_bt_mfma(const TA* __restrict__ A,
                                                    const float* __restrict__ B,
                                                    TC* __restrict__ C,
                                                    int M, int N, int K) {
    __shared__ short As[128 * 32];  // row-major [row][k], bf16 bits
    __shared__ short Bs[128 * 32];
    const int tid = threadIdx.x;
    const int lane = tid & 63;
    const int w = tid >> 6;
    const int m0 = blockIdx.y * 128;
    const int n0 = blockIdx.x * 128;
    const int wm = (w >> 1) * 64;   // wave's m-offset in tile
    const int wn = (w & 1) * 64;    // wave's n-offset in tile
    const int q = lane >> 4;        // quad 0..3
    const int mr = lane & 15;

    // staging: 512 chunks of 8 elems; chunk c -> row c>>2, cols (c&3)*8..+8
    const int c0 = tid, c1 = tid + 256;
    const int r0 = c0 >> 2, col0 = (c0 & 3) * 8;
    const int r1 = c1 >> 2, col1 = (c1 & 3) * 8;

    facc4 acc[4][4];
#pragma unroll
    for (int i = 0; i < 4; ++i)
#pragma unroll
        for (int j = 0; j < 4; ++j)
#pragma unroll
            for (int r = 0; r < 4; ++r) acc[i][j][r] = 0.f;

    for (int k0 = 0; k0 < K; k0 += 32) {
        const uint4 av0 = Stage<TA>::load8(A + (size_t)(m0 + r0) * K + k0 + col0);
        const uint4 av1 = Stage<TA>::load8(A + (size_t)(m0 + r1) * K + k0 + col1);
        const uint4 bv0 = Stage<float>::load8(B + (size_t)(n0 + r0) * K + k0 + col0);
        const uint4 bv1 = Stage<float>::load8(B + (size_t)(n0 + r1) * K + k0 + col1);
        __syncthreads();  // previous iteration's frag reads done before overwrite
        ((uint4*)As)[c0] = av0;
        ((uint4*)As)[c1] = av1;
        ((uint4*)Bs)[c0] = bv0;
        ((uint4*)Bs)[c1] = bv1;
        __syncthreads();

        frag8 af[4], bfr[4];
#pragma unroll
        for (int i = 0; i < 4; ++i)
            af[i] = *(const frag8*)&As[(wm + 16 * i + mr) * 32 + q * 8];
#pragma unroll
        for (int j = 0; j < 4; ++j)
            bfr[j] = *(const frag8*)&Bs[(wn + 16 * j + mr) * 32 + q * 8];
#pragma unroll
        for (int i = 0; i < 4; ++i)
#pragma unroll
            for (int j = 0; j < 4; ++j)
                acc[i][j] = __builtin_amdgcn_mfma_f32_16x16x32_bf16(af[i], bfr[j], acc[i][j], 0, 0, 0);
    }

    // C/D layout: col = lane&15, row = quad*4 + reg   [m89/m91-verified]
#pragma unroll
    for (int i = 0; i < 4; ++i)
#pragma unroll
        for (int j = 0; j < 4; ++j) {
            const int col = n0 + wn + 16 * j + mr;
#pragma unroll
            for (int r = 0; r < 4; ++r) {
                const int row = m0 + wm + 16 * i + q * 4 + r;
                C[(size_t)row * N + col] = fromF<TC>(acc[i][j][r]);
            }
        }
}

// ---------- RoPE (in-place on Q and K, bf16 storage, fp32 math) ----------
__global__ void rope_qk(bf16* __restrict__ Q, bf16* __restrict__ K, int S) {
    const int p = blockIdx.x * blockDim.x + threadIdx.x;
    const int total = S * NH * (HD / 2);
    if (p >= total) return;
    const int i = p % (HD / 2);
    const int rem = p / (HD / 2);
    const int h = rem % NH;
    const int s = rem / NH;
    const float inv = powf(10000.0f, -(float)(2 * i) / (float)HD);
    const float ang = (float)s * inv;
    float sn, cs;
    sincosf(ang, &sn, &cs);
    const size_t base = (size_t)s * DIM + h * HD + 2 * i;
    const float q1 = toF(Q[base]), q2 = toF(Q[base + 1]);
    Q[base] = fromF<bf16>(q1 * cs - q2 * sn);
    Q[base + 1] = fromF<bf16>(q1 * sn + q2 * cs);
    const float k1 = toF(K[base]), k2 = toF(K[base + 1]);
    K[base] = fromF<bf16>(k1 * cs - k2 * sn);
    K[base + 1] = fromF<bf16>(k1 * sn + k2 * cs);
}

// ---------- sliding-window attention: one block per (query i, head h) ----------
__global__ __launch_bounds__(256) void swa_attn(const bf16* __restrict__ Q,
                                                const bf16* __restrict__ K,
                                                const bf16* __restrict__ V,
                                                bf16* __restrict__ O, int S) {
    const int i = blockIdx.x;
    const int h = blockIdx.y;
    const int tid = threadIdx.x;
    const int lane = tid & 63;
    const int wave = tid >> 6;

    const int jlo = (i >= WIN - 1) ? i - (WIN - 1) : 0;
    const int cnt = i - jlo + 1;  // <= 512

    __shared__ float sc[WIN];
    __shared__ float red[256];

    const bf16* qrow = Q + (size_t)i * DIM + h * HD;
    const float qa = toF(qrow[2 * lane]);
    const float qb = toF(qrow[2 * lane + 1]);
    const float scale = 0.08838834764831845f;  // 1/sqrt(128)

    for (int jj = wave; jj < cnt; jj += 4) {
        const bf16* krow = K + (size_t)(jlo + jj) * DIM + h * HD;
        float pa = qa * toF(krow[2 * lane]) + qb * toF(krow[2 * lane + 1]);
#pragma unroll
        for (int off = 32; off > 0; off >>= 1) pa += __shfl_down(pa, off, 64);
        if (lane == 0) sc[jj] = pa * scale;
    }
    __syncthreads();

    float m = -1e30f;
    for (int jj = tid; jj < cnt; jj += 256) m = fmaxf(m, sc[jj]);
    red[tid] = m;
    __syncthreads();
    for (int s2 = 128; s2 > 0; s2 >>= 1) {
        if (tid < s2) red[tid] = fmaxf(red[tid], red[tid + s2]);
        __syncthreads();
    }
    m = red[0];
    __syncthreads();

    float lsum = 0.f;
    for (int jj = tid; jj < cnt; jj += 256) {
        const float e = __expf(sc[jj] - m);
        sc[jj] = e;
        lsum += e;
    }
    red[tid] = lsum;
    __syncthreads();
    for (int s2 = 128; s2 > 0; s2 >>= 1) {
        if (tid < s2) red[tid] += red[tid + s2];
        __syncthreads();
    }
    const float rinv = 1.0f / red[0];
    __syncthreads();

    const int d = tid & 127;
    const int part = tid >> 7;
    float acc = 0.f;
    for (int jj = part; jj < cnt; jj += 2) {
        acc += sc[jj] * toF(V[(size_t)(jlo + jj) * DIM + h * HD + d]);
    }
    red[tid] = acc;
    __syncthreads();
    if (tid < 128) {
        O[(size_t)i * DIM + h * HD + tid] = fromF<bf16>((red[tid] + red[tid + 128]) * rinv);
    }
}

extern "C" void kernel_launch(void* const* d_in, const int* in_sizes, int n_in,
                              void* d_out, int out_size, void* d_ws, size_t ws_size,
                              hipStream_t stream) {
    const float* x  = (const float*)d_in[0];
    const float* Wq = (const float*)d_in[1];
    const float* Wk = (const float*)d_in[2];
    const float* Wv = (const float*)d_in[3];
    const float* Wo = (const float*)d_in[4];
    float* out = (float*)d_out;

    const int S = in_sizes[0] / DIM;  // 4096
    const size_t elems = (size_t)S * DIM;

    bf16* Q = (bf16*)d_ws;
    bf16* K = Q + elems;
    bf16* V = K + elems;
    bf16* A = V + elems;   // attention output (bf16), total ws use = 67 MB

    dim3 g(DIM / 128, S / 128);  // (16, 32)
    gemm_bt_mfma<float, bf16><<<g, 256, 0, stream>>>(x, Wq, Q, S, DIM, DIM);
    gemm_bt_mfma<float, bf16><<<g, 256, 0, stream>>>(x, Wk, K, S, DIM, DIM);
    gemm_bt_mfma<float, bf16><<<g, 256, 0, stream>>>(x, Wv, V, S, DIM, DIM);

    const int pairs = S * NH * (HD / 2);
    rope_qk<<<(pairs + 255) / 256, 256, 0, stream>>>(Q, K, S);

    swa_attn<<<dim3(S, NH), 256, 0, stream>>>(Q, K, V, A, S);

    gemm_bt_mfma<bf16, float><<<g, 256, 0, stream>>>(A, Wo, out, S, DIM, DIM);
}

// Round 6
// 542.874 us; speedup vs baseline: 10.9313x; 6.6083x over previous
//
#include <hip/hip_runtime.h>
#include <hip/hip_bf16.h>
#include <math.h>

#define DIM 2048
#define NH 16
#define HD 128
#define WIN 512

typedef __hip_bfloat16 bf16;
using frag8 = __attribute__((ext_vector_type(8))) short;  // 8 bf16 (4 VGPRs)
using facc4 = __attribute__((ext_vector_type(4))) float;  // 4 fp32 acc

// ---------- conversion helpers ----------
__device__ inline float toF(const bf16 v) { return __bfloat162float(v); }
__device__ inline float toF(const float v) { return v; }
template <typename T> __device__ inline T fromF(float v);
template <> __device__ inline float fromF<float>(float v) { return v; }
template <> __device__ inline bf16 fromF<bf16>(float v) { return __float2bfloat16(v); }

// fp32 -> bf16 bits, round-to-nearest-even
__device__ inline unsigned bfb(float x) {
    unsigned u = __float_as_uint(x);
    u += 0x7fffu + ((u >> 16) & 1u);
    return u >> 16;
}

template <typename T> struct Stage;
template <> struct Stage<float> {
    __device__ static uint4 load8(const float* p) {
        const float4 v0 = *(const float4*)p;
        const float4 v1 = *(const float4*)(p + 4);
        uint4 r;
        r.x = bfb(v0.x) | (bfb(v0.y) << 16);
        r.y = bfb(v0.z) | (bfb(v0.w) << 16);
        r.z = bfb(v1.x) | (bfb(v1.y) << 16);
        r.w = bfb(v1.z) | (bfb(v1.w) << 16);
        return r;
    }
};
template <> struct Stage<bf16> {
    __device__ static uint4 load8(const bf16* p) { return *(const uint4*)p; }
};

// ---------- MFMA GEMM: C[m,n] = sum_k A[m,k] * B[n,k]  (B^T layout) ----------
template <typename TA, typename TC>
__global__ __launch_bounds__(256) void gemm_bt_mfma(const TA* __restrict__ A,
                                                    const float* __restrict__ B,
                                                    TC* __restrict__ C,
                                                    int M, int N, int K) {
    __shared__ short As[128 * 32];
    __shared__ short Bs[128 * 32];
    const int tid = threadIdx.x;
    const int lane = tid & 63;
    const int w = tid >> 6;
    const int m0 = blockIdx.y * 128;
    const int n0 = blockIdx.x * 128;
    const int wm = (w >> 1) * 64;
    const int wn = (w & 1) * 64;
    const int q = lane >> 4;
    const int mr = lane & 15;

    const int c0 = tid, c1 = tid + 256;
    const int r0 = c0 >> 2, col0 = (c0 & 3) * 8;
    const int r1 = c1 >> 2, col1 = (c1 & 3) * 8;

    facc4 acc[4][4];
#pragma unroll
    for (int i = 0; i < 4; ++i)
#pragma unroll
        for (int j = 0; j < 4; ++j)
#pragma unroll
            for (int r = 0; r < 4; ++r) acc[i][j][r] = 0.f;

    for (int k0 = 0; k0 < K; k0 += 32) {
        const uint4 av0 = Stage<TA>::load8(A + (size_t)(m0 + r0) * K + k0 + col0);
        const uint4 av1 = Stage<TA>::load8(A + (size_t)(m0 + r1) * K + k0 + col1);
        const uint4 bv0 = Stage<float>::load8(B + (size_t)(n0 + r0) * K + k0 + col0);
        const uint4 bv1 = Stage<float>::load8(B + (size_t)(n0 + r1) * K + k0 + col1);
        __syncthreads();
        ((uint4*)As)[c0] = av0;
        ((uint4*)As)[c1] = av1;
        ((uint4*)Bs)[c0] = bv0;
        ((uint4*)Bs)[c1] = bv1;
        __syncthreads();

        frag8 af[4], bfr[4];
#pragma unroll
        for (int i = 0; i < 4; ++i)
            af[i] = *(const frag8*)&As[(wm + 16 * i + mr) * 32 + q * 8];
#pragma unroll
        for (int j = 0; j < 4; ++j)
            bfr[j] = *(const frag8*)&Bs[(wn + 16 * j + mr) * 32 + q * 8];
#pragma unroll
        for (int i = 0; i < 4; ++i)
#pragma unroll
            for (int j = 0; j < 4; ++j)
                acc[i][j] = __builtin_amdgcn_mfma_f32_16x16x32_bf16(af[i], bfr[j], acc[i][j], 0, 0, 0);
    }

#pragma unroll
    for (int i = 0; i < 4; ++i)
#pragma unroll
        for (int j = 0; j < 4; ++j) {
            const int col = n0 + wn + 16 * j + mr;
#pragma unroll
            for (int r = 0; r < 4; ++r) {
                const int row = m0 + wm + 16 * i + q * 4 + r;
                C[(size_t)row * N + col] = fromF<TC>(acc[i][j][r]);
            }
        }
}

// ---------- RoPE (in-place on Q and K, bf16 storage, fp32 math) ----------
__global__ void rope_qk(bf16* __restrict__ Q, bf16* __restrict__ K, int S) {
    const int p = blockIdx.x * blockDim.x + threadIdx.x;
    const int total = S * NH * (HD / 2);
    if (p >= total) return;
    const int i = p % (HD / 2);
    const int rem = p / (HD / 2);
    const int h = rem % NH;
    const int s = rem / NH;
    const float inv = powf(10000.0f, -(float)(2 * i) / (float)HD);
    const float ang = (float)s * inv;
    float sn, cs;
    sincosf(ang, &sn, &cs);
    const size_t base = (size_t)s * DIM + h * HD + 2 * i;
    const float q1 = toF(Q[base]), q2 = toF(Q[base + 1]);
    Q[base] = fromF<bf16>(q1 * cs - q2 * sn);
    Q[base + 1] = fromF<bf16>(q1 * sn + q2 * cs);
    const float k1 = toF(K[base]), k2 = toF(K[base + 1]);
    K[base] = fromF<bf16>(k1 * cs - k2 * sn);
    K[base + 1] = fromF<bf16>(k1 * sn + k2 * cs);
}

// ---------- flash sliding-window attention ----------
// Block = 64 queries x 1 head, 256 threads (4 waves, wave w owns query rows w*16..w*16+15).
// Iterates <=9 K-tiles of 64 keys covering [i0-512, i0+63].
// LDS: Qs[64][136] (reused as Ps[64][72]) | Ks[64][136] | Vt[128][72]  = 53248 B -> 3 blocks/CU.
__global__ __launch_bounds__(256, 3) void flash_swa(const bf16* __restrict__ Q,
                                                    const bf16* __restrict__ K,
                                                    const bf16* __restrict__ V,
                                                    bf16* __restrict__ O, int S) {
    __shared__ __align__(16) char lds[53248];
    short* Qs = (short*)lds;              // [64][136]
    short* Ps = (short*)lds;              // [64][72], reuses Qs space
    short* Ks = (short*)(lds + 17408);    // [64][136]
    short* Vt = (short*)(lds + 34816);    // [128][72]  (Vt[d][k] = V[k][d])

    const int tid = threadIdx.x;
    const int lane = tid & 63;
    const int w = tid >> 6;
    const int q = lane >> 4;   // quad
    const int mr = lane & 15;
    const int i0 = blockIdx.x * 64;
    const int h = blockIdx.y;
    const float scale = 0.08838834764831845f;  // 1/sqrt(128)

    // ---- stage Q tile (64x128) ----
#pragma unroll
    for (int u = 0; u < 4; ++u) {
        const int c = tid + 256 * u;
        const int row = c >> 4, col = (c & 15) * 8;
        *(uint4*)&Qs[row * 136 + col] =
            *(const uint4*)(Q + (size_t)(i0 + row) * DIM + h * HD + col);
    }
    __syncthreads();
    frag8 qf[4];
#pragma unroll
    for (int kk = 0; kk < 4; ++kk)
        qf[kk] = *(const frag8*)&Qs[(w * 16 + mr) * 136 + kk * 32 + q * 8];

    float mrow[4], lrow[4];
    facc4 oacc[8];
#pragma unroll
    for (int r = 0; r < 4; ++r) { mrow[r] = -1e30f; lrow[r] = 0.f; }
#pragma unroll
    for (int dt = 0; dt < 8; ++dt)
#pragma unroll
        for (int r = 0; r < 4; ++r) oacc[dt][r] = 0.f;

    const int t0 = (i0 >= WIN) ? 0 : (WIN - i0) / 64;
    for (int t = t0; t < 9; ++t) {
        const int jb = i0 - WIN + t * 64;  // tile key base, always >= 0
        __syncthreads();  // prior tile's Ks/Vt reads (and qf loads) complete

        // ---- stage K tile (64x128) ----
#pragma unroll
        for (int u = 0; u < 4; ++u) {
            const int c = tid + 256 * u;
            const int row = c >> 4, col = (c & 15) * 8;
            *(uint4*)&Ks[row * 136 + col] =
                *(const uint4*)(K + (size_t)(jb + row) * DIM + h * HD + col);
        }
        // ---- stage V transposed: Vt[d][k], packing key-pairs so b32 writes span banks ----
#pragma unroll
        for (int it = 0; it < 2; ++it) {
            const int kp = lane & 31;                       // keys 2kp, 2kp+1
            const int dc = (lane >> 5) + 2 * it + 4 * w;    // d-chunk 0..15
            const int d0 = dc * 8;
            const bf16* vp = V + (size_t)(jb + 2 * kp) * DIM + h * HD + d0;
            const uint4 a = *(const uint4*)vp;
            const uint4 b = *(const uint4*)(vp + DIM);
            const uint aw[4] = {a.x, a.y, a.z, a.w};
            const uint bw[4] = {b.x, b.y, b.z, b.w};
#pragma unroll
            for (int e = 0; e < 8; ++e) {
                const uint lo = (aw[e >> 1] >> (16 * (e & 1))) & 0xFFFFu;
                const uint hi = (bw[e >> 1] >> (16 * (e & 1))) & 0xFFFFu;
                ((uint*)Vt)[(d0 + e) * 36 + kp] = lo | (hi << 16);
            }
        }
        __syncthreads();

        // ---- QK^T: wave computes 16x64 scores ----
        facc4 sacc[4];
#pragma unroll
        for (int nt = 0; nt < 4; ++nt) {
#pragma unroll
            for (int r = 0; r < 4; ++r) sacc[nt][r] = 0.f;
#pragma unroll
            for (int kk = 0; kk < 4; ++kk) {
                const frag8 kfr = *(const frag8*)&Ks[(nt * 16 + mr) * 136 + kk * 32 + q * 8];
                sacc[nt] = __builtin_amdgcn_mfma_f32_16x16x32_bf16(qf[kk], kfr, sacc[nt], 0, 0, 0);
            }
        }

        // ---- mask + scale, row max ----
        float sv[4][4];
        float rmax[4] = {-1e30f, -1e30f, -1e30f, -1e30f};
#pragma unroll
        for (int nt = 0; nt < 4; ++nt) {
            const int j = jb + nt * 16 + mr;
#pragma unroll
            for (int r = 0; r < 4; ++r) {
                const int i = i0 + w * 16 + q * 4 + r;
                const bool valid = (j <= i) && (i - j < WIN);
                sv[nt][r] = valid ? sacc[nt][r] * scale : -1e30f;
                rmax[r] = fmaxf(rmax[r], sv[nt][r]);
            }
        }
#pragma unroll
        for (int msk = 1; msk <= 8; msk <<= 1)
#pragma unroll
            for (int r = 0; r < 4; ++r)
                rmax[r] = fmaxf(rmax[r], __shfl_xor(rmax[r], msk, 64));

        // ---- online softmax update ----
        float alpha[4], rsum[4];
#pragma unroll
        for (int r = 0; r < 4; ++r) {
            const float mn = fmaxf(mrow[r], rmax[r]);
            alpha[r] = __expf(mrow[r] - mn);
            mrow[r] = mn;
            rsum[r] = 0.f;
        }
#pragma unroll
        for (int nt = 0; nt < 4; ++nt)
#pragma unroll
            for (int r = 0; r < 4; ++r) {
                const float pv = (sv[nt][r] > -1e29f) ? __expf(sv[nt][r] - mrow[r]) : 0.f;
                rsum[r] += pv;
                Ps[(w * 16 + q * 4 + r) * 72 + nt * 16 + mr] = (short)bfb(pv);
            }
#pragma unroll
        for (int msk = 1; msk <= 8; msk <<= 1)
#pragma unroll
            for (int r = 0; r < 4; ++r)
                rsum[r] += __shfl_xor(rsum[r], msk, 64);
#pragma unroll
        for (int r = 0; r < 4; ++r) lrow[r] = lrow[r] * alpha[r] + rsum[r];
#pragma unroll
        for (int dt = 0; dt < 8; ++dt)
#pragma unroll
            for (int r = 0; r < 4; ++r) oacc[dt][r] *= alpha[r];

        __syncthreads();  // Ps visible (safety; Ps is wave-private)

        // ---- P @ V: O[16 queries][128 d] per wave ----
#pragma unroll
        for (int ks = 0; ks < 2; ++ks) {
            const frag8 pf = *(const frag8*)&Ps[(w * 16 + mr) * 72 + ks * 32 + q * 8];
#pragma unroll
            for (int dt = 0; dt < 8; ++dt) {
                const frag8 vf = *(const frag8*)&Vt[(dt * 16 + mr) * 72 + ks * 32 + q * 8];
                oacc[dt] = __builtin_amdgcn_mfma_f32_16x16x32_bf16(pf, vf, oacc[dt], 0, 0, 0);
            }
        }
    }

    // ---- epilogue: O /= l, store ----
    float inv[4];
#pragma unroll
    for (int r = 0; r < 4; ++r) inv[r] = 1.0f / lrow[r];
#pragma unroll
    for (int dt = 0; dt < 8; ++dt)
#pragma unroll
        for (int r = 0; r < 4; ++r) {
            const int row = i0 + w * 16 + q * 4 + r;
            O[(size_t)row * DIM + h * HD + dt * 16 + mr] = fromF<bf16>(oacc[dt][r] * inv[r]);
        }
}

extern "C" void kernel_launch(void* const* d_in, const int* in_sizes, int n_in,
                              void* d_out, int out_size, void* d_ws, size_t ws_size,
                              hipStream_t stream) {
    const float* x  = (const float*)d_in[0];
    const float* Wq = (const float*)d_in[1];
    const float* Wk = (const float*)d_in[2];
    const float* Wv = (const float*)d_in[3];
    const float* Wo = (const float*)d_in[4];
    float* out = (float*)d_out;

    const int S = in_sizes[0] / DIM;  // 4096
    const size_t elems = (size_t)S * DIM;

    bf16* Q = (bf16*)d_ws;
    bf16* K = Q + elems;
    bf16* V = K + elems;
    bf16* A = V + elems;   // attention output, total ws use = 67 MB

    dim3 g(DIM / 128, S / 128);
    gemm_bt_mfma<float, bf16><<<g, 256, 0, stream>>>(x, Wq, Q, S, DIM, DIM);
    gemm_bt_mfma<float, bf16><<<g, 256, 0, stream>>>(x, Wk, K, S, DIM, DIM);
    gemm_bt_mfma<float, bf16><<<g, 256, 0, stream>>>(x, Wv, V, S, DIM, DIM);

    const int pairs = S * NH * (HD / 2);
    rope_qk<<<(pairs + 255) / 256, 256, 0, stream>>>(Q, K, S);

    flash_swa<<<dim3(S / 64, NH), 256, 0, stream>>>(Q, K, V, A, S);

    gemm_bt_mfma<bf16, float><<<g, 256, 0, stream>>>(A, Wo, out, S, DIM, DIM);
}

// Round 7
// 419.977 us; speedup vs baseline: 14.1301x; 1.2926x over previous
//
#include <hip/hip_runtime.h>
#include <hip/hip_bf16.h>
#include <math.h>

#define DIM 2048
#define NH 16
#define HD 128
#define WIN 512

typedef __hip_bfloat16 bf16;
using frag8 = __attribute__((ext_vector_type(8))) short;  // 8 bf16 (4 VGPRs)
using facc4 = __attribute__((ext_vector_type(4))) float;  // 4 fp32 acc

// ---------- conversion helpers ----------
__device__ inline float toF(const bf16 v) { return __bfloat162float(v); }
template <typename T> __device__ inline T fromF(float v);
template <> __device__ inline float fromF<float>(float v) { return v; }
template <> __device__ inline bf16 fromF<bf16>(float v) { return __float2bfloat16(v); }

// fp32 -> bf16 bits, round-to-nearest-even
__device__ inline unsigned bfb(float x) {
    unsigned u = __float_as_uint(x);
    u += 0x7fffu + ((u >> 16) & 1u);
    return u >> 16;
}

// pack 8 fp32 -> 8 bf16 (one uint4)
__device__ inline uint4 pack8(const float* p) {
    const float4 v0 = *(const float4*)p;
    const float4 v1 = *(const float4*)(p + 4);
    uint4 r;
    r.x = bfb(v0.x) | (bfb(v0.y) << 16);
    r.y = bfb(v0.z) | (bfb(v0.w) << 16);
    r.z = bfb(v1.x) | (bfb(v1.y) << 16);
    r.w = bfb(v1.z) | (bfb(v1.w) << 16);
    return r;
}

// ---------- fp32 -> bf16 bulk convert ----------
__global__ __launch_bounds__(256) void cvt_f32_bf16(const float* __restrict__ src,
                                                    bf16* __restrict__ dst, int n8) {
    const int i = blockIdx.x * 256 + threadIdx.x;
    if (i < n8) ((uint4*)dst)[i] = pack8(src + (size_t)i * 8);
}

// ---------- async global->LDS, 16B per lane, wave-uniform LDS base ----------
__device__ inline void gload_lds16(const bf16* g, short* l) {
    __builtin_amdgcn_global_load_lds(
        (const __attribute__((address_space(1))) unsigned int*)g,
        (__attribute__((address_space(3))) unsigned int*)l, 16, 0, 0);
}

// ---------- MFMA GEMM (m97 structure): C[m,n] = sum_k A[m,k] * B[n,k], all-bf16 inputs ----------
// 128x128 tile, BK=32, 4 waves 2x2, global_load_lds width-16 staging.
// SPLIT: N spans 3 concatenated weight blocks; write to Qp/Kp/Vp with ld=DIM.
template <typename TC, bool SPLIT>
__global__ __launch_bounds__(256) void gemm_bt_async(const bf16* __restrict__ A,
                                                     const bf16* __restrict__ B,
                                                     TC* __restrict__ C,
                                                     bf16* __restrict__ Qp,
                                                     bf16* __restrict__ Kp,
                                                     bf16* __restrict__ Vp,
                                                     int M, int N, int K) {
    __shared__ short As[128 * 32];  // row-major [row][k], no padding (global_load_lds constraint)
    __shared__ short Bs[128 * 32];
    const int tid = threadIdx.x;
    const int lane = tid & 63;
    const int w = tid >> 6;
    const int m0 = blockIdx.y * 128;
    const int n0 = blockIdx.x * 128;
    const int wm = (w >> 1) * 64;
    const int wn = (w & 1) * 64;
    const int q = lane >> 4;
    const int mr = lane & 15;

    facc4 acc[4][4];
#pragma unroll
    for (int i = 0; i < 4; ++i)
#pragma unroll
        for (int j = 0; j < 4; ++j)
#pragma unroll
            for (int r = 0; r < 4; ++r) acc[i][j][r] = 0.f;

    for (int k0 = 0; k0 < K; k0 += 32) {
        __syncthreads();  // prior iteration's frag reads complete before overwrite
#pragma unroll
        for (int u = 0; u < 2; ++u) {
            const int c = w * 128 + u * 64 + lane;      // chunk id; lds dest = base + lane*16B
            const int row = c >> 2, col = (c & 3) * 8;
            gload_lds16(A + (size_t)(m0 + row) * K + k0 + col, As + (w * 128 + u * 64) * 8);
            gload_lds16(B + (size_t)(n0 + row) * K + k0 + col, Bs + (w * 128 + u * 64) * 8);
        }
        __syncthreads();  // drains vmcnt: staged data visible

        frag8 af[4], bfr[4];
#pragma unroll
        for (int i = 0; i < 4; ++i)
            af[i] = *(const frag8*)&As[(wm + 16 * i + mr) * 32 + q * 8];
#pragma unroll
        for (int j = 0; j < 4; ++j)
            bfr[j] = *(const frag8*)&Bs[(wn + 16 * j + mr) * 32 + q * 8];
#pragma unroll
        for (int i = 0; i < 4; ++i)
#pragma unroll
            for (int j = 0; j < 4; ++j)
                acc[i][j] = __builtin_amdgcn_mfma_f32_16x16x32_bf16(af[i], bfr[j], acc[i][j], 0, 0, 0);
    }

    // C/D layout: col = lane&15, row = quad*4 + reg
    if (SPLIT) {
        bf16* dst = (n0 < DIM) ? Qp : ((n0 < 2 * DIM) ? Kp : Vp);
        const int nb = n0 % DIM;
#pragma unroll
        for (int i = 0; i < 4; ++i)
#pragma unroll
            for (int j = 0; j < 4; ++j) {
                const int col = nb + wn + 16 * j + mr;
#pragma unroll
                for (int r = 0; r < 4; ++r) {
                    const int row = m0 + wm + 16 * i + q * 4 + r;
                    dst[(size_t)row * DIM + col] = fromF<bf16>(acc[i][j][r]);
                }
            }
    } else {
#pragma unroll
        for (int i = 0; i < 4; ++i)
#pragma unroll
            for (int j = 0; j < 4; ++j) {
                const int col = n0 + wn + 16 * j + mr;
#pragma unroll
                for (int r = 0; r < 4; ++r) {
                    const int row = m0 + wm + 16 * i + q * 4 + r;
                    C[(size_t)row * N + col] = fromF<TC>(acc[i][j][r]);
                }
            }
    }
}

// ---------- RoPE (in-place on Q and K, bf16 storage, fp32 math) ----------
__global__ void rope_qk(bf16* __restrict__ Q, bf16* __restrict__ K, int S) {
    const int p = blockIdx.x * blockDim.x + threadIdx.x;
    const int total = S * NH * (HD / 2);
    if (p >= total) return;
    const int i = p % (HD / 2);
    const int rem = p / (HD / 2);
    const int h = rem % NH;
    const int s = rem / NH;
    const float inv = powf(10000.0f, -(float)(2 * i) / (float)HD);
    const float ang = (float)s * inv;
    float sn, cs;
    sincosf(ang, &sn, &cs);
    const size_t base = (size_t)s * DIM + h * HD + 2 * i;
    const float q1 = toF(Q[base]), q2 = toF(Q[base + 1]);
    Q[base] = fromF<bf16>(q1 * cs - q2 * sn);
    Q[base + 1] = fromF<bf16>(q1 * sn + q2 * cs);
    const float k1 = toF(K[base]), k2 = toF(K[base + 1]);
    K[base] = fromF<bf16>(k1 * cs - k2 * sn);
    K[base + 1] = fromF<bf16>(k1 * sn + k2 * cs);
}

// ---------- flash sliding-window attention (unchanged from round 5) ----------
__global__ __launch_bounds__(256, 3) void flash_swa(const bf16* __restrict__ Q,
                                                    const bf16* __restrict__ K,
                                                    const bf16* __restrict__ V,
                                                    bf16* __restrict__ O, int S) {
    __shared__ __align__(16) char lds[53248];
    short* Qs = (short*)lds;              // [64][136]
    short* Ps = (short*)lds;              // [64][72], reuses Qs space
    short* Ks = (short*)(lds + 17408);    // [64][136]
    short* Vt = (short*)(lds + 34816);    // [128][72]  (Vt[d][k] = V[k][d])

    const int tid = threadIdx.x;
    const int lane = tid & 63;
    const int w = tid >> 6;
    const int q = lane >> 4;
    const int mr = lane & 15;
    const int i0 = blockIdx.x * 64;
    const int h = blockIdx.y;
    const float scale = 0.08838834764831845f;

#pragma unroll
    for (int u = 0; u < 4; ++u) {
        const int c = tid + 256 * u;
        const int row = c >> 4, col = (c & 15) * 8;
        *(uint4*)&Qs[row * 136 + col] =
            *(const uint4*)(Q + (size_t)(i0 + row) * DIM + h * HD + col);
    }
    __syncthreads();
    frag8 qf[4];
#pragma unroll
    for (int kk = 0; kk < 4; ++kk)
        qf[kk] = *(const frag8*)&Qs[(w * 16 + mr) * 136 + kk * 32 + q * 8];

    float mrow[4], lrow[4];
    facc4 oacc[8];
#pragma unroll
    for (int r = 0; r < 4; ++r) { mrow[r] = -1e30f; lrow[r] = 0.f; }
#pragma unroll
    for (int dt = 0; dt < 8; ++dt)
#pragma unroll
        for (int r = 0; r < 4; ++r) oacc[dt][r] = 0.f;

    const int t0 = (i0 >= WIN) ? 0 : (WIN - i0) / 64;
    for (int t = t0; t < 9; ++t) {
        const int jb = i0 - WIN + t * 64;
        __syncthreads();

#pragma unroll
        for (int u = 0; u < 4; ++u) {
            const int c = tid + 256 * u;
            const int row = c >> 4, col = (c & 15) * 8;
            *(uint4*)&Ks[row * 136 + col] =
                *(const uint4*)(K + (size_t)(jb + row) * DIM + h * HD + col);
        }
#pragma unroll
        for (int it = 0; it < 2; ++it) {
            const int kp = lane & 31;
            const int dc = (lane >> 5) + 2 * it + 4 * w;
            const int d0 = dc * 8;
            const bf16* vp = V + (size_t)(jb + 2 * kp) * DIM + h * HD + d0;
            const uint4 a = *(const uint4*)vp;
            const uint4 b = *(const uint4*)(vp + DIM);
            const uint aw[4] = {a.x, a.y, a.z, a.w};
            const uint bw[4] = {b.x, b.y, b.z, b.w};
#pragma unroll
            for (int e = 0; e < 8; ++e) {
                const uint lo = (aw[e >> 1] >> (16 * (e & 1))) & 0xFFFFu;
                const uint hi = (bw[e >> 1] >> (16 * (e & 1))) & 0xFFFFu;
                ((uint*)Vt)[(d0 + e) * 36 + kp] = lo | (hi << 16);
            }
        }
        __syncthreads();

        facc4 sacc[4];
#pragma unroll
        for (int nt = 0; nt < 4; ++nt) {
#pragma unroll
            for (int r = 0; r < 4; ++r) sacc[nt][r] = 0.f;
#pragma unroll
            for (int kk = 0; kk < 4; ++kk) {
                const frag8 kfr = *(const frag8*)&Ks[(nt * 16 + mr) * 136 + kk * 32 + q * 8];
                sacc[nt] = __builtin_amdgcn_mfma_f32_16x16x32_bf16(qf[kk], kfr, sacc[nt], 0, 0, 0);
            }
        }

        float sv[4][4];
        float rmax[4] = {-1e30f, -1e30f, -1e30f, -1e30f};
#pragma unroll
        for (int nt = 0; nt < 4; ++nt) {
            const int j = jb + nt * 16 + mr;
#pragma unroll
            for (int r = 0; r < 4; ++r) {
                const int i = i0 + w * 16 + q * 4 + r;
                const bool valid = (j <= i) && (i - j < WIN);
                sv[nt][r] = valid ? sacc[nt][r] * scale : -1e30f;
                rmax[r] = fmaxf(rmax[r], sv[nt][r]);
            }
        }
#pragma unroll
        for (int msk = 1; msk <= 8; msk <<= 1)
#pragma unroll
            for (int r = 0; r < 4; ++r)
                rmax[r] = fmaxf(rmax[r], __shfl_xor(rmax[r], msk, 64));

        float alpha[4], rsum[4];
#pragma unroll
        for (int r = 0; r < 4; ++r) {
            const float mn = fmaxf(mrow[r], rmax[r]);
            alpha[r] = __expf(mrow[r] - mn);
            mrow[r] = mn;
            rsum[r] = 0.f;
        }
#pragma unroll
        for (int nt = 0; nt < 4; ++nt)
#pragma unroll
            for (int r = 0; r < 4; ++r) {
                const float pv = (sv[nt][r] > -1e29f) ? __expf(sv[nt][r] - mrow[r]) : 0.f;
                rsum[r] += pv;
                Ps[(w * 16 + q * 4 + r) * 72 + nt * 16 + mr] = (short)bfb(pv);
            }
#pragma unroll
        for (int msk = 1; msk <= 8; msk <<= 1)
#pragma unroll
            for (int r = 0; r < 4; ++r)
                rsum[r] += __shfl_xor(rsum[r], msk, 64);
#pragma unroll
        for (int r = 0; r < 4; ++r) lrow[r] = lrow[r] * alpha[r] + rsum[r];
#pragma unroll
        for (int dt = 0; dt < 8; ++dt)
#pragma unroll
            for (int r = 0; r < 4; ++r) oacc[dt][r] *= alpha[r];

        __syncthreads();

#pragma unroll
        for (int ks = 0; ks < 2; ++ks) {
            const frag8 pf = *(const frag8*)&Ps[(w * 16 + mr) * 72 + ks * 32 + q * 8];
#pragma unroll
            for (int dt = 0; dt < 8; ++dt) {
                const frag8 vf = *(const frag8*)&Vt[(dt * 16 + mr) * 72 + ks * 32 + q * 8];
                oacc[dt] = __builtin_amdgcn_mfma_f32_16x16x32_bf16(pf, vf, oacc[dt], 0, 0, 0);
            }
        }
    }

    float inv[4];
#pragma unroll
    for (int r = 0; r < 4; ++r) inv[r] = 1.0f / lrow[r];
#pragma unroll
    for (int dt = 0; dt < 8; ++dt)
#pragma unroll
        for (int r = 0; r < 4; ++r) {
            const int row = i0 + w * 16 + q * 4 + r;
            O[(size_t)row * DIM + h * HD + dt * 16 + mr] = fromF<bf16>(oacc[dt][r] * inv[r]);
        }
}

extern "C" void kernel_launch(void* const* d_in, const int* in_sizes, int n_in,
                              void* d_out, int out_size, void* d_ws, size_t ws_size,
                              hipStream_t stream) {
    const float* x  = (const float*)d_in[0];
    const float* Wq = (const float*)d_in[1];
    const float* Wk = (const float*)d_in[2];
    const float* Wv = (const float*)d_in[3];
    const float* Wo = (const float*)d_in[4];
    float* out = (float*)d_out;

    const int S = in_sizes[0] / DIM;          // 4096
    const size_t elems = (size_t)S * DIM;     // 8.39M
    const size_t wsz = (size_t)DIM * DIM;     // 4.19M

    bf16* Q    = (bf16*)d_ws;
    bf16* K    = Q + elems;
    bf16* V    = K + elems;
    bf16* Aat  = V + elems;
    bf16* xb   = Aat + elems;
    bf16* Wcat = xb + elems;    // [3*DIM][DIM]: Wq | Wk | Wv
    bf16* Wob  = Wcat + 3 * wsz;
    // total ws use: (5*elems + 4*wsz)*2B = 117 MB

    // ---- fp32 -> bf16 conversions ----
    cvt_f32_bf16<<<(int)(elems / 8 / 256), 256, 0, stream>>>(x, xb, (int)(elems / 8));
    cvt_f32_bf16<<<(int)(wsz / 8 / 256), 256, 0, stream>>>(Wq, Wcat, (int)(wsz / 8));
    cvt_f32_bf16<<<(int)(wsz / 8 / 256), 256, 0, stream>>>(Wk, Wcat + wsz, (int)(wsz / 8));
    cvt_f32_bf16<<<(int)(wsz / 8 / 256), 256, 0, stream>>>(Wv, Wcat + 2 * wsz, (int)(wsz / 8));
    cvt_f32_bf16<<<(int)(wsz / 8 / 256), 256, 0, stream>>>(Wo, Wob, (int)(wsz / 8));

    // ---- fused QKV projection: [S x 2048] @ [6144 x 2048]^T ----
    gemm_bt_async<bf16, true><<<dim3(3 * DIM / 128, S / 128), 256, 0, stream>>>(
        xb, Wcat, (bf16*)nullptr, Q, K, V, S, 3 * DIM, DIM);

    const int pairs = S * NH * (HD / 2);
    rope_qk<<<(pairs + 255) / 256, 256, 0, stream>>>(Q, K, S);

    flash_swa<<<dim3(S / 64, NH), 256, 0, stream>>>(Q, K, V, Aat, S);

    // ---- output projection ----
    gemm_bt_async<float, false><<<dim3(DIM / 128, S / 128), 256, 0, stream>>>(
        Aat, Wob, out, nullptr, nullptr, nullptr, S, DIM, DIM);
}

// Round 8
// 412.170 us; speedup vs baseline: 14.3977x; 1.0189x over previous
//
#include <hip/hip_runtime.h>
#include <hip/hip_bf16.h>
#include <math.h>

#define DIM 2048
#define NH 16
#define HD 128
#define WIN 512

typedef __hip_bfloat16 bf16;
using frag8 = __attribute__((ext_vector_type(8))) short;  // 8 bf16 (4 VGPRs)
using facc4 = __attribute__((ext_vector_type(4))) float;  // 4 fp32 acc

// ---------- conversion helpers ----------
__device__ inline float toF(const bf16 v) { return __bfloat162float(v); }
template <typename T> __device__ inline T fromF(float v);
template <> __device__ inline float fromF<float>(float v) { return v; }
template <> __device__ inline bf16 fromF<bf16>(float v) { return __float2bfloat16(v); }

// fp32 -> bf16 bits, round-to-nearest-even
__device__ inline unsigned bfb(float x) {
    unsigned u = __float_as_uint(x);
    u += 0x7fffu + ((u >> 16) & 1u);
    return u >> 16;
}

// pack 8 fp32 -> 8 bf16 (one uint4)
__device__ inline uint4 pack8(const float* p) {
    const float4 v0 = *(const float4*)p;
    const float4 v1 = *(const float4*)(p + 4);
    uint4 r;
    r.x = bfb(v0.x) | (bfb(v0.y) << 16);
    r.y = bfb(v0.z) | (bfb(v0.w) << 16);
    r.z = bfb(v1.x) | (bfb(v1.y) << 16);
    r.w = bfb(v1.z) | (bfb(v1.w) << 16);
    return r;
}

// ---------- fp32 -> bf16 bulk convert ----------
__global__ __launch_bounds__(256) void cvt_f32_bf16(const float* __restrict__ src,
                                                    bf16* __restrict__ dst, int n8) {
    const int i = blockIdx.x * 256 + threadIdx.x;
    if (i < n8) ((uint4*)dst)[i] = pack8(src + (size_t)i * 8);
}

// ---------- async global->LDS, 16B per lane, wave-uniform LDS base ----------
__device__ inline void gload_lds16(const bf16* g, short* l) {
    __builtin_amdgcn_global_load_lds(
        (const __attribute__((address_space(1))) unsigned int*)g,
        (__attribute__((address_space(3))) unsigned int*)l, 16, 0, 0);
}

// ---------- MFMA GEMM (m97 structure): C[m,n] = sum_k A[m,k] * B[n,k], all-bf16 inputs ----------
template <typename TC, bool SPLIT>
__global__ __launch_bounds__(256) void gemm_bt_async(const bf16* __restrict__ A,
                                                     const bf16* __restrict__ B,
                                                     TC* __restrict__ C,
                                                     bf16* __restrict__ Qp,
                                                     bf16* __restrict__ Kp,
                                                     bf16* __restrict__ Vp,
                                                     int M, int N, int K) {
    __shared__ short As[128 * 32];  // row-major [row][k], no padding (global_load_lds constraint)
    __shared__ short Bs[128 * 32];
    const int tid = threadIdx.x;
    const int lane = tid & 63;
    const int w = tid >> 6;
    const int m0 = blockIdx.y * 128;
    const int n0 = blockIdx.x * 128;
    const int wm = (w >> 1) * 64;
    const int wn = (w & 1) * 64;
    const int q = lane >> 4;
    const int mr = lane & 15;

    facc4 acc[4][4];
#pragma unroll
    for (int i = 0; i < 4; ++i)
#pragma unroll
        for (int j = 0; j < 4; ++j)
#pragma unroll
            for (int r = 0; r < 4; ++r) acc[i][j][r] = 0.f;

    for (int k0 = 0; k0 < K; k0 += 32) {
        __syncthreads();
#pragma unroll
        for (int u = 0; u < 2; ++u) {
            const int c = w * 128 + u * 64 + lane;
            const int row = c >> 2, col = (c & 3) * 8;
            gload_lds16(A + (size_t)(m0 + row) * K + k0 + col, As + (w * 128 + u * 64) * 8);
            gload_lds16(B + (size_t)(n0 + row) * K + k0 + col, Bs + (w * 128 + u * 64) * 8);
        }
        __syncthreads();

        frag8 af[4], bfr[4];
#pragma unroll
        for (int i = 0; i < 4; ++i)
            af[i] = *(const frag8*)&As[(wm + 16 * i + mr) * 32 + q * 8];
#pragma unroll
        for (int j = 0; j < 4; ++j)
            bfr[j] = *(const frag8*)&Bs[(wn + 16 * j + mr) * 32 + q * 8];
#pragma unroll
        for (int i = 0; i < 4; ++i)
#pragma unroll
            for (int j = 0; j < 4; ++j)
                acc[i][j] = __builtin_amdgcn_mfma_f32_16x16x32_bf16(af[i], bfr[j], acc[i][j], 0, 0, 0);
    }

    if (SPLIT) {
        bf16* dst = (n0 < DIM) ? Qp : ((n0 < 2 * DIM) ? Kp : Vp);
        const int nb = n0 % DIM;
#pragma unroll
        for (int i = 0; i < 4; ++i)
#pragma unroll
            for (int j = 0; j < 4; ++j) {
                const int col = nb + wn + 16 * j + mr;
#pragma unroll
                for (int r = 0; r < 4; ++r) {
                    const int row = m0 + wm + 16 * i + q * 4 + r;
                    dst[(size_t)row * DIM + col] = fromF<bf16>(acc[i][j][r]);
                }
            }
    } else {
#pragma unroll
        for (int i = 0; i < 4; ++i)
#pragma unroll
            for (int j = 0; j < 4; ++j) {
                const int col = n0 + wn + 16 * j + mr;
#pragma unroll
                for (int r = 0; r < 4; ++r) {
                    const int row = m0 + wm + 16 * i + q * 4 + r;
                    C[(size_t)row * N + col] = fromF<TC>(acc[i][j][r]);
                }
            }
    }
}

// ---------- vectorized RoPE: 8 elems (4 pairs) per thread ----------
__device__ inline uint rot_pair(uint wp, float c, float s) {
    const float x1 = __uint_as_float((wp & 0xFFFFu) << 16);
    const float x2 = __uint_as_float(wp & 0xFFFF0000u);
    const float r1 = x1 * c - x2 * s;
    const float r2 = x1 * s + x2 * c;
    return bfb(r1) | (bfb(r2) << 16);
}

__global__ __launch_bounds__(256) void rope_qk_vec(bf16* __restrict__ Q,
                                                   bf16* __restrict__ K, int S) {
    const int p = blockIdx.x * 256 + threadIdx.x;  // p < S*DIM/8
    const int per_row = DIM / 8;
    const int s = p / per_row;
    const int off = (p % per_row) * 8;
    const int f0 = (off & 127) >> 1;  // pair index within head
    float cs[4], sn[4];
#pragma unroll
    for (int t = 0; t < 4; ++t) {
        // inv_freq = 10000^(-(f0+t)/64) = exp(-0.14391157*(f0+t)); relative-rotation
        // property of RoPE makes the ~1e-6 rel freq error harmless.
        const float inv = __expf(-0.14391157f * (float)(f0 + t));
        sincosf((float)s * inv, &sn[t], &cs[t]);
    }
    const size_t base = (size_t)s * DIM + off;
    uint4 qv = *(uint4*)(Q + base);
    qv.x = rot_pair(qv.x, cs[0], sn[0]);
    qv.y = rot_pair(qv.y, cs[1], sn[1]);
    qv.z = rot_pair(qv.z, cs[2], sn[2]);
    qv.w = rot_pair(qv.w, cs[3], sn[3]);
    *(uint4*)(Q + base) = qv;
    uint4 kv = *(uint4*)(K + base);
    kv.x = rot_pair(kv.x, cs[0], sn[0]);
    kv.y = rot_pair(kv.y, cs[1], sn[1]);
    kv.z = rot_pair(kv.z, cs[2], sn[2]);
    kv.w = rot_pair(kv.w, cs[3], sn[3]);
    *(uint4*)(K + base) = kv;
}

// ---------- one-time V transpose: V[s][h*128+d] -> Vt[h][d][s] ----------
__global__ __launch_bounds__(256) void transp_v(const bf16* __restrict__ V,
                                                bf16* __restrict__ Vt, int S) {
    const int tid = threadIdx.x;
    const int lane = tid & 63;
    const int w = tid >> 6;
    const int k0 = blockIdx.x * 64;
    const int h = blockIdx.y;
#pragma unroll
    for (int it = 0; it < 2; ++it) {
        const int kp = lane & 31;                     // key pair 2kp, 2kp+1
        const int dc = (lane >> 5) + 2 * it + 4 * w;  // d-chunk 0..15
        const int d0 = dc * 8;
        const bf16* vp = V + (size_t)(k0 + 2 * kp) * DIM + h * HD + d0;
        const uint4 a = *(const uint4*)vp;
        const uint4 b = *(const uint4*)(vp + DIM);
        const uint aw[4] = {a.x, a.y, a.z, a.w};
        const uint bw[4] = {b.x, b.y, b.z, b.w};
#pragma unroll
        for (int e = 0; e < 8; ++e) {
            const uint lo = (aw[e >> 1] >> (16 * (e & 1))) & 0xFFFFu;
            const uint hi = (bw[e >> 1] >> (16 * (e & 1))) & 0xFFFFu;
            ((uint*)Vt)[((((size_t)h * HD + d0 + e) * S + k0) >> 1) + kp] = lo | (hi << 16);
        }
    }
}

// ---------- flash sliding-window attention (reads pre-transposed Vt) ----------
// Block = 64 queries x 1 head, 256 threads (4 waves, wave w owns query rows w*16..w*16+15).
// LDS: Qs[64][136] (reused as Ps[64][72]) | Ks[64][136] | VtL[128][72]  = 53248 B -> 3 blocks/CU.
__global__ __launch_bounds__(256, 3) void flash_swa(const bf16* __restrict__ Q,
                                                    const bf16* __restrict__ K,
                                                    const bf16* __restrict__ Vt,
                                                    bf16* __restrict__ O, int S) {
    __shared__ __align__(16) char lds[53248];
    short* Qs = (short*)lds;               // [64][136]
    short* Ps = (short*)lds;               // [64][72], reuses Qs space
    short* Ks = (short*)(lds + 17408);     // [64][136]
    short* VtL = (short*)(lds + 34816);    // [128][72]  (VtL[d][k])

    const int tid = threadIdx.x;
    const int lane = tid & 63;
    const int w = tid >> 6;
    const int q = lane >> 4;
    const int mr = lane & 15;
    const int i0 = blockIdx.x * 64;
    const int h = blockIdx.y;
    const float scale = 0.08838834764831845f;

#pragma unroll
    for (int u = 0; u < 4; ++u) {
        const int c = tid + 256 * u;
        const int row = c >> 4, col = (c & 15) * 8;
        *(uint4*)&Qs[row * 136 + col] =
            *(const uint4*)(Q + (size_t)(i0 + row) * DIM + h * HD + col);
    }
    __syncthreads();
    frag8 qf[4];
#pragma unroll
    for (int kk = 0; kk < 4; ++kk)
        qf[kk] = *(const frag8*)&Qs[(w * 16 + mr) * 136 + kk * 32 + q * 8];

    float mrow[4], lrow[4];
    facc4 oacc[8];
#pragma unroll
    for (int r = 0; r < 4; ++r) { mrow[r] = -1e30f; lrow[r] = 0.f; }
#pragma unroll
    for (int dt = 0; dt < 8; ++dt)
#pragma unroll
        for (int r = 0; r < 4; ++r) oacc[dt][r] = 0.f;

    const bf16* vtg = Vt + (size_t)h * HD * S;

    const int t0 = (i0 >= WIN) ? 0 : (WIN - i0) / 64;
    for (int t = t0; t < 9; ++t) {
        const int jb = i0 - WIN + t * 64;
        __syncthreads();

        // ---- stage K tile (64x128) ----
#pragma unroll
        for (int u = 0; u < 4; ++u) {
            const int c = tid + 256 * u;
            const int row = c >> 4, col = (c & 15) * 8;
            *(uint4*)&Ks[row * 136 + col] =
                *(const uint4*)(K + (size_t)(jb + row) * DIM + h * HD + col);
        }
        // ---- stage Vt tile [128 d][64 k]: straight copy from global Vt ----
#pragma unroll
        for (int u = 0; u < 4; ++u) {
            const int c = tid + 256 * u;              // 1024 chunks of 8
            const int d = c >> 3, k0c = (c & 7) * 8;
            *(uint4*)&VtL[d * 72 + k0c] = *(const uint4*)(vtg + (size_t)d * S + jb + k0c);
        }
        __syncthreads();

        // ---- QK^T: wave computes 16x64 scores ----
        facc4 sacc[4];
#pragma unroll
        for (int nt = 0; nt < 4; ++nt) {
#pragma unroll
            for (int r = 0; r < 4; ++r) sacc[nt][r] = 0.f;
#pragma unroll
            for (int kk = 0; kk < 4; ++kk) {
                const frag8 kfr = *(const frag8*)&Ks[(nt * 16 + mr) * 136 + kk * 32 + q * 8];
                sacc[nt] = __builtin_amdgcn_mfma_f32_16x16x32_bf16(qf[kk], kfr, sacc[nt], 0, 0, 0);
            }
        }

        float sv[4][4];
        float rmax[4] = {-1e30f, -1e30f, -1e30f, -1e30f};
#pragma unroll
        for (int nt = 0; nt < 4; ++nt) {
            const int j = jb + nt * 16 + mr;
#pragma unroll
            for (int r = 0; r < 4; ++r) {
                const int i = i0 + w * 16 + q * 4 + r;
                const bool valid = (j <= i) && (i - j < WIN);
                sv[nt][r] = valid ? sacc[nt][r] * scale : -1e30f;
                rmax[r] = fmaxf(rmax[r], sv[nt][r]);
            }
        }
#pragma unroll
        for (int msk = 1; msk <= 8; msk <<= 1)
#pragma unroll
            for (int r = 0; r < 4; ++r)
                rmax[r] = fmaxf(rmax[r], __shfl_xor(rmax[r], msk, 64));

        float alpha[4], rsum[4];
#pragma unroll
        for (int r = 0; r < 4; ++r) {
            const float mn = fmaxf(mrow[r], rmax[r]);
            alpha[r] = __expf(mrow[r] - mn);
            mrow[r] = mn;
            rsum[r] = 0.f;
        }
#pragma unroll
        for (int nt = 0; nt < 4; ++nt)
#pragma unroll
            for (int r = 0; r < 4; ++r) {
                const float pv = (sv[nt][r] > -1e29f) ? __expf(sv[nt][r] - mrow[r]) : 0.f;
                rsum[r] += pv;
                Ps[(w * 16 + q * 4 + r) * 72 + nt * 16 + mr] = (short)bfb(pv);
            }
#pragma unroll
        for (int msk = 1; msk <= 8; msk <<= 1)
#pragma unroll
            for (int r = 0; r < 4; ++r)
                rsum[r] += __shfl_xor(rsum[r], msk, 64);
#pragma unroll
        for (int r = 0; r < 4; ++r) lrow[r] = lrow[r] * alpha[r] + rsum[r];
#pragma unroll
        for (int dt = 0; dt < 8; ++dt)
#pragma unroll
            for (int r = 0; r < 4; ++r) oacc[dt][r] *= alpha[r];

        __syncthreads();

#pragma unroll
        for (int ks = 0; ks < 2; ++ks) {
            const frag8 pf = *(const frag8*)&Ps[(w * 16 + mr) * 72 + ks * 32 + q * 8];
#pragma unroll
            for (int dt = 0; dt < 8; ++dt) {
                const frag8 vf = *(const frag8*)&VtL[(dt * 16 + mr) * 72 + ks * 32 + q * 8];
                oacc[dt] = __builtin_amdgcn_mfma_f32_16x16x32_bf16(pf, vf, oacc[dt], 0, 0, 0);
            }
        }
    }

    float inv[4];
#pragma unroll
    for (int r = 0; r < 4; ++r) inv[r] = 1.0f / lrow[r];
#pragma unroll
    for (int dt = 0; dt < 8; ++dt)
#pragma unroll
        for (int r = 0; r < 4; ++r) {
            const int row = i0 + w * 16 + q * 4 + r;
            O[(size_t)row * DIM + h * HD + dt * 16 + mr] = fromF<bf16>(oacc[dt][r] * inv[r]);
        }
}

extern "C" void kernel_launch(void* const* d_in, const int* in_sizes, int n_in,
                              void* d_out, int out_size, void* d_ws, size_t ws_size,
                              hipStream_t stream) {
    const float* x  = (const float*)d_in[0];
    const float* Wq = (const float*)d_in[1];
    const float* Wk = (const float*)d_in[2];
    const float* Wv = (const float*)d_in[3];
    const float* Wo = (const float*)d_in[4];
    float* out = (float*)d_out;

    const int S = in_sizes[0] / DIM;          // 4096
    const size_t elems = (size_t)S * DIM;     // 8.39M
    const size_t wsz = (size_t)DIM * DIM;     // 4.19M

    bf16* Q    = (bf16*)d_ws;
    bf16* K    = Q + elems;
    bf16* V    = K + elems;
    bf16* Aat  = V + elems;
    bf16* xb   = Aat + elems;   // x(bf16) for QKV GEMM; dead after -> reused as Vt
    bf16* Wcat = xb + elems;    // [3*DIM][DIM]: Wq | Wk | Wv
    bf16* Wob  = Wcat + 3 * wsz;
    bf16* Vt   = xb;            // Vt[h][d][S], reuses xb (dead after QKV GEMM)
    // total ws use: (5*elems + 4*wsz)*2B = 117 MB

    cvt_f32_bf16<<<(int)(elems / 8 / 256), 256, 0, stream>>>(x, xb, (int)(elems / 8));
    cvt_f32_bf16<<<(int)(wsz / 8 / 256), 256, 0, stream>>>(Wq, Wcat, (int)(wsz / 8));
    cvt_f32_bf16<<<(int)(wsz / 8 / 256), 256, 0, stream>>>(Wk, Wcat + wsz, (int)(wsz / 8));
    cvt_f32_bf16<<<(int)(wsz / 8 / 256), 256, 0, stream>>>(Wv, Wcat + 2 * wsz, (int)(wsz / 8));
    cvt_f32_bf16<<<(int)(wsz / 8 / 256), 256, 0, stream>>>(Wo, Wob, (int)(wsz / 8));

    // fused QKV projection: [S x 2048] @ [6144 x 2048]^T
    gemm_bt_async<bf16, true><<<dim3(3 * DIM / 128, S / 128), 256, 0, stream>>>(
        xb, Wcat, (bf16*)nullptr, Q, K, V, S, 3 * DIM, DIM);

    rope_qk_vec<<<(int)(elems / 8 / 256), 256, 0, stream>>>(Q, K, S);

    transp_v<<<dim3(S / 64, NH), 256, 0, stream>>>(V, Vt, S);

    flash_swa<<<dim3(S / 64, NH), 256, 0, stream>>>(Q, K, Vt, Aat, S);

    gemm_bt_async<float, false><<<dim3(DIM / 128, S / 128), 256, 0, stream>>>(
        Aat, Wob, out, nullptr, nullptr, nullptr, S, DIM, DIM);
}